// Round 11
// baseline (69.407 us; speedup 1.0000x reference)
//
#include <hip/hip_runtime.h>

typedef float f4  __attribute__((ext_vector_type(4)));
typedef short s8v __attribute__((ext_vector_type(8)));
typedef short s4v __attribute__((ext_vector_type(4)));

#define BB    2
#define DDIM  1024
#define LSEQ  8192
#define LC    128
#define TD    16      // channels per block = 4 groups, 1 group per wave
#define TILE  512     // l-extent per tile
#define NT    4       // tiles per block (block spans 2048 l)
#define SPAN  (TILE*NT)
#define ZW2   520     // bf16 per row per buffer: 512 + 8 pad (odd 16B stride)
#define KSTR  176     // padded filter row: index = m + KOFF, m ∈ [-16, 160)
#define KOFF  16
#define OB2   64      // f4 per row: half-tile (256 l) output staging

__device__ __forceinline__ unsigned bf16pk(float lo, float hi) {
    unsigned a = __float_as_uint(lo), b = __float_as_uint(hi);
    a = (a + 0x7FFFu + ((a >> 16) & 1u)) >> 16;
    b = (b + 0x7FFFu + ((b >> 16) & 1u));
    return (a & 0xFFFFu) | (b & 0xFFFF0000u);
}
__device__ __forceinline__ float bf2f(short s) {
    return __uint_as_float(((unsigned)(unsigned short)s) << 16);
}

union U8 { s8v s; unsigned u[4]; };

__device__ __forceinline__ s8v cvt8(const f4& a0, const f4& a1, const f4& w0, const f4& w1) {
    const f4 z0 = a0*w0, z1 = a1*w1;
    U8 zz;
    zz.u[0] = bf16pk(z0[0], z0[1]);
    zz.u[1] = bf16pk(z0[2], z0[3]);
    zz.u[2] = bf16pk(z1[0], z1[1]);
    zz.u[3] = bf16pk(z1[2], z1[3]);
    return zz.s;
}

// LDS 51.3KB -> 3 blocks/CU; bounds(256,3) caps VGPR ~170 (NO tighter: R6/R7 spilled)
__global__ __launch_bounds__(256, 3) void hyena_pipe_kernel(
    const float* __restrict__ x1,
    const float* __restrict__ x2,
    const float* __restrict__ v,
    const float* __restrict__ h,
    const float* __restrict__ cb,
    float* __restrict__ out)
{
    __shared__ short zb[2][TD][ZW2];   // double-buffered z tiles (halo = prev buffer tail)
    __shared__ float kl[4][KSTR];      // decay filters (built once)
    __shared__ f4    ob[TD][OB2];      // output transpose staging (half tile)

    const int t = threadIdx.x;

    // XCD decode: each XCD owns one (b, l-quarter) -> its 64 d0-blocks assemble
    // full 4KB output lines in the XCD's L2. (round-robin xcd = flat % 8)
    const int flat = blockIdx.x;
    const int xcd  = flat & 7;
    const int d0   = (flat >> 3) * TD;   // [0,1024) step 16
    const int lg   = xcd & 3;
    const int b    = xcd >> 2;
    const int bl0  = lg * SPAN;

    const int r = t & 15, sbase = t >> 4;
    const size_t rb = ((size_t)(b*DDIM + d0 + r)) * LSEQ;

    // ---- prologue: issue tile0 + halo loads (20 f4 in flight) ----
    f4 pa0[4], pa1[4], pw0[4], pw1[4];
    #pragma unroll
    for (int it = 0; it < 4; ++it) {
        const int gl = bl0 + (sbase + 16*it)*8;
        pa0[it] = *(const f4*)(x2 + rb + gl);
        pa1[it] = *(const f4*)(x2 + rb + gl + 4);
        pw0[it] = *(const f4*)(v  + rb + gl);
        pw1[it] = *(const f4*)(v  + rb + gl + 4);
    }
    const int hgl = bl0 - 128 + sbase*8;
    f4 ha0 = {0,0,0,0}, ha1 = ha0, hw0 = ha0, hw1 = ha0;
    if (hgl >= 0) {
        ha0 = *(const f4*)(x2 + rb + hgl);
        ha1 = *(const f4*)(x2 + rb + hgl + 4);
        hw0 = *(const f4*)(v  + rb + hgl);
        hw1 = *(const f4*)(v  + rb + hgl + 4);
    }

    // ---- filter build (overlaps staging-load latency) ----
    for (int idx = t; idx < 4*KSTR; idx += 256) {
        const int gl2 = idx / KSTR, mi = idx - gl2*KSTR;
        const int m  = mi - KOFF;
        float val = 0.f;
        if (m >= 0 && m < LC) {
            const int g = (d0 >> 2) + gl2;
            const float dd = __expf((float)g * (2.0f/255.0f) * 2.302585092994046f);
            val = h[g*LC + m] * __expf(-dd * (float)m * (1.0f/127.0f));
        }
        kl[gl2][mi] = val;
    }

    // ---- convert + ds_write: tile0 -> zb[0], halo -> zb[1] tail ----
    #pragma unroll
    for (int it = 0; it < 4; ++it)
        *(s8v*)&zb[0][r][(sbase + 16*it)*8] = cvt8(pa0[it], pa1[it], pw0[it], pw1[it]);
    { s8v hz = (hgl >= 0) ? cvt8(ha0, ha1, hw0, hw1) : (s8v){0,0,0,0,0,0,0,0};
      *(s8v*)&zb[1][r][384 + sbase*8] = hz; }

    // ---- lane geometry ----
    const int wv = t >> 6, lane = t & 63;
    const int j  = lane & 15, kb = lane >> 4;
    const int qj = j & 3,  cc = j >> 2;
    const int row = wv*4 + cc;
    const float bd = cb[d0 + row];
    const size_t chbase = ((size_t)(b*DDIM + d0 + row)) * LSEQ + bl0;
    const int seg = t & 3;
    __syncthreads();

    // ---- A-frags (once per block): A_u[i,p] = k_pad[i - p + 16 + 32u] ----
    s8v afr[5];
    #pragma unroll
    for (int u = 0; u < 5; ++u) {
        const int M0 = j - 8*kb + 16 + 32*u;
        float kv[8];
        #pragma unroll
        for (int e = 0; e < 8; ++e) kv[e] = kl[wv][M0 - e + KOFF];
        U8 aa;
        aa.u[0] = bf16pk(kv[0], kv[1]);
        aa.u[1] = bf16pk(kv[2], kv[3]);
        aa.u[2] = bf16pk(kv[4], kv[5]);
        aa.u[3] = bf16pk(kv[6], kv[7]);
        afr[u] = aa.s;
    }

    // ==== pipelined tile loop ====
    for (int tt = 0; tt < NT; ++tt) {
        short (*cur)[ZW2] = zb[tt & 1];         // tile tt
        short (*prv)[ZW2] = zb[(tt + 1) & 1];   // tail = tile tt-1 / halo; dest for tt+1
        const bool stage = (tt + 1 < NT);
        const int tl0 = bl0 + (tt + 1)*TILE;

        // -- issue half-A of tile tt+1 (q in [0,256)) --
        f4 sa0[2], sa1[2], sw0[2], sw1[2];
        if (stage) {
            #pragma unroll
            for (int it = 0; it < 2; ++it) {
                const int gl = tl0 + (sbase + 16*it)*8;
                sa0[it] = *(const f4*)(x2 + rb + gl);
                sa1[it] = *(const f4*)(x2 + rb + gl + 4);
                sw0[it] = *(const f4*)(v  + rb + gl);
                sw1[it] = *(const f4*)(v  + rb + gl + 4);
            }
        }

        // -- chains for tile tt (reads cur + prv tail) --
        const size_t chb = chbase + (size_t)tt*TILE;
        f4 x1a[4], x1b[4];
        #pragma unroll
        for (int ci = 0; ci < 4; ++ci)
            x1a[ci] = *(const f4*)(x1 + chb + 64*ci + 16*qj + 4*kb);
        f4 ov[8];
        #pragma unroll
        for (int ci = 0; ci < 8; ++ci) {
            if (ci == 4) {
                #pragma unroll
                for (int c2 = 0; c2 < 4; ++c2)
                    x1b[c2] = *(const f4*)(x1 + chb + 64*(c2+4) + 16*qj + 4*kb);
            }
            const int qb = 64*ci + 16*qj + 8*kb - 16;
            f4 acc = {0.f, 0.f, 0.f, 0.f};
            #pragma unroll
            for (int u = 0; u < 5; ++u) {
                const int q = qb - 32*u;
                const short* p = (q >= 0) ? &cur[row][q]
                                          : &prv[row][512 + (q < -128 ? -128 : q)];
                const s8v bf = *(const s8v*)p;
                acc = __builtin_amdgcn_mfma_f32_16x16x32_bf16(afr[u], bf, acc, 0, 0, 0);
            }
            const int lo = 64*ci + 16*qj + 4*kb;
            const s4v z4 = *(const s4v*)&cur[row][lo];
            const f4 xv = (ci < 4) ? x1a[ci] : x1b[ci-4];
            f4 o;
            o[0] = (acc[0] + bf2f(z4[0])*bd) * xv[0];
            o[1] = (acc[1] + bf2f(z4[1])*bd) * xv[1];
            o[2] = (acc[2] + bf2f(z4[2])*bd) * xv[2];
            o[3] = (acc[3] + bf2f(z4[3])*bd) * xv[3];
            ov[ci] = o;
        }

        // -- issue half-B of tile tt+1 (q in [256,512)) --
        f4 ta0[2], ta1[2], tw0[2], tw1[2];
        if (stage) {
            #pragma unroll
            for (int it = 0; it < 2; ++it) {
                const int gl = tl0 + (sbase + 16*(it+2))*8;
                ta0[it] = *(const f4*)(x2 + rb + gl);
                ta1[it] = *(const f4*)(x2 + rb + gl + 4);
                tw0[it] = *(const f4*)(v  + rb + gl);
                tw1[it] = *(const f4*)(v  + rb + gl + 4);
            }
        }

        __syncthreads();                                   // (1) all chains done

        if (stage) {                                       // ds_write half-A -> prv
            #pragma unroll
            for (int it = 0; it < 2; ++it)
                *(s8v*)&prv[r][(sbase + 16*it)*8] = cvt8(sa0[it], sa1[it], sw0[it], sw1[it]);
        }
        #pragma unroll
        for (int ci = 0; ci < 4; ++ci) {                   // ob-write half 1
            const int J = (4*ci + qj)*4 + kb;
            ob[row][J ^ (row & 7)] = ov[ci];
        }
        __syncthreads();                                   // (2)

        #pragma unroll
        for (int it = 0; it < 4; ++it) {                   // ob-read half 1 -> store
            const int ll = (t >> 2) + it*64;
            const int J = ll >> 2, e = ll & 3;
            f4 o;
            #pragma unroll
            for (int rr2 = 0; rr2 < 4; ++rr2) {
                const int r2 = seg*4 + rr2;
                o[rr2] = ((const float*)&ob[r2][J ^ (r2 & 7)])[e];
            }
            *(f4*)(out + ((size_t)b*LSEQ + bl0 + tt*TILE + ll)*DDIM + d0 + seg*4) = o;
        }
        if (stage) {                                       // ds_write half-B -> prv
            #pragma unroll
            for (int it = 0; it < 2; ++it)
                *(s8v*)&prv[r][(sbase + 16*(it+2))*8] = cvt8(ta0[it], ta1[it], tw0[it], tw1[it]);
        }
        __syncthreads();                                   // (3)

        #pragma unroll
        for (int ci = 4; ci < 8; ++ci) {                   // ob-write half 2
            const int J = (4*ci + qj)*4 + kb - 64;
            ob[row][J ^ (row & 7)] = ov[ci];
        }
        __syncthreads();                                   // (4)

        #pragma unroll
        for (int it = 0; it < 4; ++it) {                   // ob-read half 2 -> store
            const int ll = (t >> 2) + it*64;
            const int J = ll >> 2, e = ll & 3;
            f4 o;
            #pragma unroll
            for (int rr2 = 0; rr2 < 4; ++rr2) {
                const int r2 = seg*4 + rr2;
                o[rr2] = ((const float*)&ob[r2][J ^ (r2 & 7)])[e];
            }
            *(f4*)(out + ((size_t)b*LSEQ + bl0 + tt*TILE + 256 + ll)*DDIM + d0 + seg*4) = o;
        }
    }
}

extern "C" void kernel_launch(void* const* d_in, const int* in_sizes, int n_in,
                              void* d_out, int out_size, void* d_ws, size_t ws_size,
                              hipStream_t stream) {
    const float* x1 = (const float*)d_in[0];
    const float* x2 = (const float*)d_in[1];
    const float* v  = (const float*)d_in[2];
    const float* h  = (const float*)d_in[3];
    const float* cb = (const float*)d_in[4];
    float* outp = (float*)d_out;
    hipLaunchKernelGGL(hyena_pipe_kernel, dim3(512), dim3(256), 0, stream,
                       x1, x2, v, h, cb, outp);
}

// Round 12
// 50.942 us; speedup vs baseline: 1.3625x; 1.3625x over previous
//
#include <hip/hip_runtime.h>

typedef float f4  __attribute__((ext_vector_type(4)));
typedef short s8v __attribute__((ext_vector_type(8)));
typedef short s4v __attribute__((ext_vector_type(4)));

#define BB    2
#define DDIM  1024
#define LSEQ  8192
#define LC    128
#define TD    16      // channels per block = 4 groups, 1 group per wave
#define TL    512     // l-extent per block
#define HALO  128
#define ZSTR  648     // bf16 row stride: 640 data + 8 pad
#define OB2   (TL/8)  // 64 f4 per row: half-tile output staging (16 KB)

// round-to-nearest-even fp32 -> bf16, packed pair (lo in bits 0-15)
__device__ __forceinline__ unsigned bf16pk(float lo, float hi) {
    unsigned a = __float_as_uint(lo), b = __float_as_uint(hi);
    a = (a + 0x7FFFu + ((a >> 16) & 1u)) >> 16;
    b = (b + 0x7FFFu + ((b >> 16) & 1u));
    return (a & 0xFFFFu) | (b & 0xFFFF0000u);
}
__device__ __forceinline__ float bf2f(short s) {
    return __uint_as_float(((unsigned)(unsigned short)s) << 16);
}

union U8 { s8v s; unsigned u[4]; };

// NOTE: min-waves arg MUST stay 4 (VGPR cap 128). 5/6 forced VGPR<=102/85 and
// spilled the phase-0 staged tile to scratch (R6: WRITE 215MB, R7: FETCH+52MB).
// NOTE2: occupancy is wave-slot capped (8 waves/blk x 4 blk = 32), NOT LDS-capped;
// LDS cuts below 32KB buy pipe relief, not residency.
__global__ __launch_bounds__(256, 4) void hyena_mfma_kernel(
    const float* __restrict__ x1,
    const float* __restrict__ x2,
    const float* __restrict__ v,
    const float* __restrict__ h,
    const float* __restrict__ cb,
    float* __restrict__ out)
{
    __shared__ union SM {
        short zb[TD][ZSTR];   // z (bf16) tile + halo (20.25 KB)
        f4 ob[TD][OB2];       // fp32 out staging, half tile (16 KB)
    } sm;

    const int t = threadIdx.x;

    // ---- XCD-aware decode: all 64 d0-blocks of one (l0,b) share an XCD so the
    //      XCD's L2 assembles full 4KB output lines (round-robin xcd = flat%8) ----
    const int flat = blockIdx.x;
    const int xcd  = flat & 7;
    const int rr_  = flat >> 3;
    const int d0   = (rr_ & 63) * TD;
    const int c_   = xcd + 8*(rr_ >> 6);        // [0,32)
    const int l0   = (c_ & 15) * TL;
    const int b    = c_ >> 4;

    // ---- phase 0: issue ALL z-staging loads into registers (long-latency first) ----
    const int r = t & 15, sbase = t >> 4;
    const size_t rb = ((size_t)(b*DDIM + d0 + r)) * LSEQ;
    f4 xa0[5], xa1[5], xw0[5], xw1[5];
    #pragma unroll
    for (int it = 0; it < 5; ++it) {
        const int gl = l0 - HALO + (sbase + 16*it)*8;
        if (gl >= 0) {
            xa0[it] = *(const f4*)(x2 + rb + gl);
            xa1[it] = *(const f4*)(x2 + rb + gl + 4);
            xw0[it] = *(const f4*)(v  + rb + gl);
            xw1[it] = *(const f4*)(v  + rb + gl + 4);
        }
    }

    // ---- convert staged regs -> bf16 z in LDS ----
    #pragma unroll
    for (int it = 0; it < 5; ++it) {
        const int s = sbase + 16*it;
        const int gl = l0 - HALO + s*8;
        U8 zz; zz.s = (s8v){0,0,0,0,0,0,0,0};
        if (gl >= 0) {
            const f4 z0 = xa0[it]*xw0[it], z1 = xa1[it]*xw1[it];
            zz.u[0] = bf16pk(z0[0], z0[1]);
            zz.u[1] = bf16pk(z0[2], z0[3]);
            zz.u[2] = bf16pk(z1[0], z1[1]);
            zz.u[3] = bf16pk(z1[2], z1[3]);
        }
        *(s8v*)&sm.zb[r][s*8] = zz.s;
    }

    // ---- lane geometry (MFMA 16x16x32) + early x1 prefetch (before barrier) ----
    const int wv = t >> 6, lane = t & 63;
    const int j  = lane & 15, kb = lane >> 4;
    const int qj = j & 3,  cc = j >> 2;
    const int row = wv*4 + cc;
    const size_t chb = ((size_t)(b*DDIM + d0 + row)) * LSEQ + l0;
    f4 x1r[8];
    #pragma unroll
    for (int ci = 0; ci < 8; ++ci)
        x1r[ci] = *(const f4*)(x1 + chb + 64*ci + 16*qj + 4*kb);
    const float bd = cb[d0 + row];

    // ---- A-frags IN REGISTERS (no LDS): A_u[i,p] = k[i - p + 16 + 32u],
    //      k[m] = h[g,m]*exp(-dd*m/127), m OOB -> 0. Exp via recurrence:
    //      w_e = base_u * r^e (r = e^{dd/127}), base_{u+1} = base_u * s. ----
    const int g = (d0 >> 2) + wv;
    const float* __restrict__ hg = h + g*LC;
    const float dd = __expf((float)g * (2.0f/255.0f) * 2.302585092994046f); // 10^(2g/255)
    const float t0 = dd * (1.0f/127.0f);
    const int   M0base = j - 8*kb + 16;          // m at e=0, u=0
    const float rE = __expf(t0);                 // e^{t0}
    const float sU = __expf(-32.0f*t0);          // e^{-32 t0}
    float pE[8];                                 // r^e
    pE[0] = 1.0f;
    #pragma unroll
    for (int e = 1; e < 8; ++e) pE[e] = pE[e-1]*rE;
    float baseU = __expf(-t0*(float)M0base);

    s8v afr[5];
    #pragma unroll
    for (int u = 0; u < 5; ++u) {
        const int M0 = M0base + 32*u;
        float kv[8];
        #pragma unroll
        for (int e = 0; e < 8; ++e) {
            const int m = M0 - e;
            const int mc = m < 0 ? 0 : (m > 127 ? 127 : m);
            const float hv = hg[mc];                         // L1/L2-hot dword
            const float w  = ((unsigned)m < 128u) ? baseU*pE[e] : 0.0f;
            kv[e] = hv * w;
        }
        U8 aa;
        aa.u[0] = bf16pk(kv[0], kv[1]);
        aa.u[1] = bf16pk(kv[2], kv[3]);
        aa.u[2] = bf16pk(kv[4], kv[5]);
        aa.u[3] = bf16pk(kv[6], kv[7]);
        afr[u] = aa.s;
        baseU *= sU;
    }
    __syncthreads();

    // ---- 8 chains: 5 banded-Toeplitz MFMAs each; bias from LDS bf16 z; gate x1 ----
    f4 ov[8];
    #pragma unroll
    for (int ci = 0; ci < 8; ++ci) {
        const int L = 64*ci + 16*qj;
        f4 acc = {0.f, 0.f, 0.f, 0.f};
        #pragma unroll
        for (int u = 0; u < 5; ++u) {
            int bi = 112 + L + 8*kb - 32*u;      // zb idx of B_u[p=8kb..], incl. halo
            bi = bi < 0 ? 0 : bi;                // clamped reads pair with A == 0
            const s8v bf = *(const s8v*)&sm.zb[row][bi];
            acc = __builtin_amdgcn_mfma_f32_16x16x32_bf16(afr[u], bf, acc, 0, 0, 0);
        }
        const int lo = L + 4*kb;                 // lane's 4 output l's: lo..lo+3
        const s4v z4 = *(const s4v*)&sm.zb[row][HALO + lo];
        f4 o;
        o[0] = (acc[0] + bf2f(z4[0])*bd) * x1r[ci][0];
        o[1] = (acc[1] + bf2f(z4[1])*bd) * x1r[ci][1];
        o[2] = (acc[2] + bf2f(z4[2])*bd) * x1r[ci][2];
        o[3] = (acc[3] + bf2f(z4[3])*bd) * x1r[ci][3];
        ov[ci] = o;
    }

    // ---- output transpose in two 16 KB half-phases (z dead after first barrier) ----
    const int seg = t & 3;
    #pragma unroll
    for (int hp = 0; hp < 2; ++hp) {
        __syncthreads();                         // ob free (zb dead / prev half drained)
        #pragma unroll
        for (int ci = 0; ci < 4; ++ci) {
            const int cidx = hp*4 + ci;
            const int J = (4*cidx + qj)*4 + kb - hp*64;   // [0,64)
            sm.ob[row][J ^ (row & 7)] = ov[cidx];
        }
        __syncthreads();
        #pragma unroll
        for (int it = 0; it < 4; ++it) {
            const int ll = (t >> 2) + it*64;     // local l in [0,256)
            const int J = ll >> 2, e = ll & 3;
            f4 o;
            #pragma unroll
            for (int rr2 = 0; rr2 < 4; ++rr2) {
                const int r2 = seg*4 + rr2;
                o[rr2] = ((const float*)&sm.ob[r2][J ^ (r2 & 7)])[e];
            }
            __builtin_nontemporal_store(o,
                (f4*)(out + ((size_t)b*LSEQ + l0 + hp*256 + ll)*DDIM + d0 + seg*4));
        }
    }
}

extern "C" void kernel_launch(void* const* d_in, const int* in_sizes, int n_in,
                              void* d_out, int out_size, void* d_ws, size_t ws_size,
                              hipStream_t stream) {
    const float* x1 = (const float*)d_in[0];
    const float* x2 = (const float*)d_in[1];
    const float* v  = (const float*)d_in[2];
    const float* h  = (const float*)d_in[3];
    const float* cb = (const float*)d_in[4];
    float* outp = (float*)d_out;
    hipLaunchKernelGGL(hyena_mfma_kernel, dim3(2048), dim3(256), 0, stream,
                       x1, x2, v, h, cb, outp);
}